// Round 1
// baseline (142.383 us; speedup 1.0000x reference)
//
#include <hip/hip_runtime.h>

// Periodic radius graph: out[i][j][k] = |(frac[j]-frac[i]+off[k]) @ cell|
// masked to (d2 > 1e-12 && d < 5.0), else 0.
// N=1024 atoms, 27 images -> 28,311,552 fp32 outputs (113.2 MB). Write-BW bound.

#define NATOMS 1024
#define NIMG 27
#define CUTOFF_F 5.0f
#define TOTAL (NATOMS * NATOMS * NIMG)   // 28,311,552 — divisible by 256

__global__ __launch_bounds__(256) void PeriodicRadiusGraph_kernel(
    const float* __restrict__ frac,   // [1024, 3]
    const float* __restrict__ cell,   // [3, 3]
    float* __restrict__ out)          // [1024, 1024, 27]
{
    unsigned idx = blockIdx.x * 256u + threadIdx.x;   // < TOTAL exactly

    unsigned k = idx % 27u;
    unsigned t = idx / 27u;
    unsigned j = t & (NATOMS - 1u);
    unsigned i = t >> 10;

    // cell rows (wave-uniform -> scalar loads)
    float c00 = cell[0], c01 = cell[1], c02 = cell[2];
    float c10 = cell[3], c11 = cell[4], c12 = cell[5];
    float c20 = cell[6], c21 = cell[7], c22 = cell[8];

    // image offset decode, meshgrid(g,g,g,indexing="ij").reshape(27,3) order:
    // offsets[k] = (g[k/9], g[(k/3)%3], g[k%3]) with g = {-1,0,1}
    float ox = (float)((int)(k / 9u) - 1);
    float oy = (float)((int)((k / 3u) % 3u) - 1);
    float oz = (float)((int)(k % 3u) - 1);

    float fx = frac[3u * j + 0u] - frac[3u * i + 0u] + ox;
    float fy = frac[3u * j + 1u] - frac[3u * i + 1u] + oy;
    float fz = frac[3u * j + 2u] - frac[3u * i + 2u] + oz;

    // row-vector convention: vec_e = sum_d dfrac_d * cell[d][e]
    float vx = fx * c00 + fy * c10 + fz * c20;
    float vy = fx * c01 + fy * c11 + fz * c21;
    float vz = fx * c02 + fy * c12 + fz * c22;

    float d2 = vx * vx + vy * vy + vz * vz;
    float d  = sqrtf(d2);
    float r  = (d2 > 1e-12f && d < CUTOFF_F) ? d : 0.0f;

    out[idx] = r;
}

extern "C" void kernel_launch(void* const* d_in, const int* in_sizes, int n_in,
                              void* d_out, int out_size, void* d_ws, size_t ws_size,
                              hipStream_t stream) {
    const float* frac = (const float*)d_in[0];
    const float* cell = (const float*)d_in[1];
    float* out = (float*)d_out;

    const int block = 256;
    const int grid = TOTAL / block;   // 110592, exact
    PeriodicRadiusGraph_kernel<<<grid, block, 0, stream>>>(frac, cell, out);
}

// Round 2
// 120.762 us; speedup vs baseline: 1.1790x; 1.1790x over previous
//
#include <hip/hip_runtime.h>

// Periodic radius graph: out[i][j][k] = |(frac[j]-frac[i]+off[k]) @ cell|
// masked to (d2 > 1e-12 && d < 5.0), else 0. N=1024, 27 images.
// 113.2 MB fp32 output -> write-BW bound, floor ~18 us at 6.4 TB/s.
//
// Structure: one thread per (i,j) pair, k-loop fully unrolled (offsets become
// compile-time constants). Results staged in LDS (stride 27 dwords, 27 coprime
// with 32 banks -> conflict-free), then coalesced float4 write-out.
// Math expression order identical to round-1 kernel (which matched np bit-exact).

#define NATOMS 1024
#define NIMG 27
#define CUTOFF_F 5.0f
#define PAIRS_PER_BLOCK 256
#define FLOATS_PER_BLOCK (PAIRS_PER_BLOCK * NIMG)   // 6912 floats = 27648 B LDS
#define VEC4_PER_BLOCK (FLOATS_PER_BLOCK / 4)       // 1728

__global__ __launch_bounds__(256) void PeriodicRadiusGraph_kernel(
    const float* __restrict__ frac,   // [1024, 3]
    const float* __restrict__ cell,   // [3, 3]
    float* __restrict__ out)          // [1024, 1024, 27] flat
{
    __shared__ float tile[FLOATS_PER_BLOCK];

    const unsigned t = threadIdx.x;
    const unsigned q = blockIdx.x * PAIRS_PER_BLOCK + t;  // pair index i*1024 + j
    const unsigned j = q & (NATOMS - 1u);
    const unsigned i = q >> 10;                           // uniform within block

    // cell rows (wave-uniform -> scalar loads)
    const float c00 = cell[0], c01 = cell[1], c02 = cell[2];
    const float c10 = cell[3], c11 = cell[4], c12 = cell[5];
    const float c20 = cell[6], c21 = cell[7], c22 = cell[8];

    const float fix = frac[3u * i + 0u], fiy = frac[3u * i + 1u], fiz = frac[3u * i + 2u];
    const float fjx = frac[3u * j + 0u], fjy = frac[3u * j + 1u], fjz = frac[3u * j + 2u];

    // frac[j] - frac[i]; adding the constant offset after is bit-identical to
    // the reference's (fj - fi + o) left-to-right evaluation.
    const float dfx = fjx - fix;
    const float dfy = fjy - fiy;
    const float dfz = fjz - fiz;

    float* row = &tile[t * NIMG];

#pragma unroll
    for (int k = 0; k < NIMG; ++k) {
        // meshgrid(indexing="ij") order: (k/9, (k/3)%3, k%3) - 1  — all
        // compile-time constants after unroll; +0.0f folds away.
        const float ox = (float)(k / 9 - 1);
        const float oy = (float)((k / 3) % 3 - 1);
        const float oz = (float)(k % 3 - 1);

        const float fx = dfx + ox;
        const float fy = dfy + oy;
        const float fz = dfz + oz;

        const float vx = fx * c00 + fy * c10 + fz * c20;
        const float vy = fx * c01 + fy * c11 + fz * c21;
        const float vz = fx * c02 + fy * c12 + fz * c22;

        const float d2 = vx * vx + vy * vy + vz * vz;
        const float d  = sqrtf(d2);
        row[k] = (d2 > 1e-12f && d < CUTOFF_F) ? d : 0.0f;
    }

    __syncthreads();

    // Block's output region is flat [6912*b, 6912*(b+1)) — 16B aligned.
    // Coalesced float4 write-out: 1728 float4 per block, 256 threads,
    // 6 full rounds + 192-wide tail.
    float4* out4 = (float4*)(out + (size_t)blockIdx.x * FLOATS_PER_BLOCK);
    const float4* tile4 = (const float4*)tile;
#pragma unroll
    for (int c = 0; c < 7; ++c) {
        const int l = c * 256 + (int)t;
        if (l < VEC4_PER_BLOCK) out4[l] = tile4[l];
    }
}

extern "C" void kernel_launch(void* const* d_in, const int* in_sizes, int n_in,
                              void* d_out, int out_size, void* d_ws, size_t ws_size,
                              hipStream_t stream) {
    const float* frac = (const float*)d_in[0];
    const float* cell = (const float*)d_in[1];
    float* out = (float*)d_out;

    const int grid = (NATOMS * NATOMS) / PAIRS_PER_BLOCK;  // 4096 blocks, exact
    PeriodicRadiusGraph_kernel<<<grid, PAIRS_PER_BLOCK, 0, stream>>>(frac, cell, out);
}

// Round 3
// 118.361 us; speedup vs baseline: 1.2030x; 1.0203x over previous
//
#include <hip/hip_runtime.h>

// Periodic radius graph: out[i][j][k] = |(frac[j]-frac[i]+off[k]) @ cell|
// masked to (d2 > 1e-12 && d < 5.0), else 0. N=1024, 27 images.
// 113.2 MB fp32 output -> write-BW bound, floor ~18 us at 6.4 TB/s.
//
// One thread per (i,j) pair, k unrolled (offsets are compile-time consts).
// LDS staging (stride 27 dwords, coprime with 32 banks -> 2-way=free), then
// coalesced float4 write-out.
//
// Numerics: d2 expression identical to the round-1 kernel that matched numpy
// BIT-EXACTLY. Mask uses d2 < 25.0f which is exactly equivalent to
// IEEE-sqrt(d2) < 5.0f (monotone, sqrt(25)=5 exact) -> mask bit-identical to
// reference. Value uses raw v_sqrt_f32 (<=1 ulp, ~3e-7 abs) instead of the
// ~11-instr IEEE OCML sqrt sequence — the round-2 VALU hog.

#define NATOMS 1024
#define NIMG 27
#define PAIRS_PER_BLOCK 256
#define FLOATS_PER_BLOCK (PAIRS_PER_BLOCK * NIMG)   // 6912 floats = 27648 B LDS
#define VEC4_PER_BLOCK (FLOATS_PER_BLOCK / 4)       // 1728

__global__ __launch_bounds__(256) void PeriodicRadiusGraph_kernel(
    const float* __restrict__ frac,   // [1024, 3]
    const float* __restrict__ cell,   // [3, 3]
    float* __restrict__ out)          // [1024, 1024, 27] flat
{
    __shared__ float tile[FLOATS_PER_BLOCK];

    const unsigned t = threadIdx.x;
    const unsigned q = blockIdx.x * PAIRS_PER_BLOCK + t;  // pair index i*1024 + j
    const unsigned j = q & (NATOMS - 1u);
    const unsigned i = q >> 10;                           // uniform within block

    // cell rows (wave-uniform -> scalar loads)
    const float c00 = cell[0], c01 = cell[1], c02 = cell[2];
    const float c10 = cell[3], c11 = cell[4], c12 = cell[5];
    const float c20 = cell[6], c21 = cell[7], c22 = cell[8];

    const float fix = frac[3u * i + 0u], fiy = frac[3u * i + 1u], fiz = frac[3u * i + 2u];
    const float fjx = frac[3u * j + 0u], fjy = frac[3u * j + 1u], fjz = frac[3u * j + 2u];

    // (fj - fi) + off  — same left-to-right order as the reference.
    const float dfx = fjx - fix;
    const float dfy = fjy - fiy;
    const float dfz = fjz - fiz;

    float* row = &tile[t * NIMG];

#pragma unroll
    for (int k = 0; k < NIMG; ++k) {
        // meshgrid(indexing="ij") order: (k/9, (k/3)%3, k%3) - 1 — compile-time.
        const float ox = (float)(k / 9 - 1);
        const float oy = (float)((k / 3) % 3 - 1);
        const float oz = (float)(k % 3 - 1);

        const float fx = dfx + ox;
        const float fy = dfy + oy;
        const float fz = dfz + oz;

        const float vx = fx * c00 + fy * c10 + fz * c20;
        const float vy = fx * c01 + fy * c11 + fz * c21;
        const float vz = fx * c02 + fy * c12 + fz * c22;

        const float d2 = vx * vx + vy * vy + vz * vz;
        // Mask from d2 only (bit-identical to ref); value from fast HW sqrt.
        const float d  = __builtin_amdgcn_sqrtf(d2);
        row[k] = (d2 > 1e-12f && d2 < 25.0f) ? d : 0.0f;
    }

    __syncthreads();

    // Coalesced float4 write-out of the block's flat 6912-float region.
    float4* out4 = (float4*)(out + (size_t)blockIdx.x * FLOATS_PER_BLOCK);
    const float4* tile4 = (const float4*)tile;
#pragma unroll
    for (int c = 0; c < 7; ++c) {
        const int l = c * 256 + (int)t;
        if (l < VEC4_PER_BLOCK) out4[l] = tile4[l];
    }
}

extern "C" void kernel_launch(void* const* d_in, const int* in_sizes, int n_in,
                              void* d_out, int out_size, void* d_ws, size_t ws_size,
                              hipStream_t stream) {
    const float* frac = (const float*)d_in[0];
    const float* cell = (const float*)d_in[1];
    float* out = (float*)d_out;

    const int grid = (NATOMS * NATOMS) / PAIRS_PER_BLOCK;  // 4096 blocks, exact
    PeriodicRadiusGraph_kernel<<<grid, PAIRS_PER_BLOCK, 0, stream>>>(frac, cell, out);
}